// Round 1
// baseline (251.077 us; speedup 1.0000x reference)
//
#include <hip/hip_runtime.h>

#define HD 16

// out-layer: y = t @ W2 + b2   (W2 is [16][16] row-major, uniform -> s_load)
__device__ __forceinline__ void outlin16(const float t[HD], const float* __restrict__ W,
                                         const float* __restrict__ b, float y[HD]) {
  #pragma unroll
  for (int j = 0; j < HD; ++j) {
    float a = b[j];
    #pragma unroll
    for (int k = 0; k < HD; ++k) a = fmaf(t[k], W[k * HD + j], a);
    y[j] = a;
  }
}

__global__ void __launch_bounds__(256) egnn_fwd(
    const float* __restrict__ nf,     // (B,2,2)
    const float* __restrict__ dist,   // (B,)
    const float* __restrict__ dz,     // (B,)
    const float* __restrict__ s2p,    // (B,)
    const float* __restrict__ neW1, const float* __restrict__ neb1,
    const float* __restrict__ neW2, const float* __restrict__ neb2,
    const float* __restrict__ eeW1, const float* __restrict__ eeb1,
    const float* __restrict__ eeW2, const float* __restrict__ eeb2,
    const float* __restrict__ msgW1, const float* __restrict__ msgb1,
    const float* __restrict__ msgW2, const float* __restrict__ msgb2,
    const float* __restrict__ updW1, const float* __restrict__ updb1,
    const float* __restrict__ updW2, const float* __restrict__ updb2,
    const float* __restrict__ clsW1, const float* __restrict__ clsb1,
    const float* __restrict__ clsW2, const float* __restrict__ clsb2,
    float* __restrict__ out, int B)
{
  const int i = blockIdx.x * blockDim.x + threadIdx.x;
  if (i >= B) return;

  // ---- load per-element inputs (coalesced) ----
  const float4 nfe = *reinterpret_cast<const float4*>(nf + (size_t)i * 4);
  const float x_nf[2][2] = {{nfe.x, nfe.y}, {nfe.z, nfe.w}};
  const float ex[3] = {dist[i], dz[i], s2p[i]};

  // ---- node embedding: MLP(2 -> 16 -> 16) per node ----
  float h[2][16];
  #pragma unroll
  for (int n = 0; n < 2; ++n) {
    float t[16];
    #pragma unroll
    for (int j = 0; j < HD; ++j) {
      float a = neb1[j];
      a = fmaf(x_nf[n][0], neW1[0 * HD + j], a);
      a = fmaf(x_nf[n][1], neW1[1 * HD + j], a);
      t[j] = fmaxf(a, 0.0f);
    }
    outlin16(t, neW2, neb2, h[n]);
  }

  // ---- edge embedding: MLP(3 -> 16 -> 16) ----
  float ee[16];
  {
    float t[16];
    #pragma unroll
    for (int j = 0; j < HD; ++j) {
      float a = eeb1[j];
      a = fmaf(ex[0], eeW1[0 * HD + j], a);
      a = fmaf(ex[1], eeW1[1 * HD + j], a);
      a = fmaf(ex[2], eeW1[2 * HD + j], a);
      t[j] = fmaxf(a, 0.0f);
    }
    outlin16(t, eeW2, eeb2, ee);
  }

  // ---- message-passing layers ----
  #pragma unroll 1            // keep code size down; weight bases stay SGPR-uniform
  for (int l = 0; l < 2; ++l) {
    const float* __restrict__ mW1 = msgW1 + l * 48 * HD;
    const float* __restrict__ mb1 = msgb1 + l * HD;
    const float* __restrict__ mW2 = msgW2 + l * HD * HD;
    const float* __restrict__ mb2 = msgb2 + l * HD;
    const float* __restrict__ uW1 = updW1 + l * 32 * HD;
    const float* __restrict__ ub1 = updb1 + l * HD;
    const float* __restrict__ uW2 = updW2 + l * HD * HD;
    const float* __restrict__ ub2 = updb2 + l * HD;

    float msg[2][16];
    #pragma unroll
    for (int d = 0; d < 2; ++d) {          // msg_01 (d=0) and msg_10 (d=1)
      float t[16];
      #pragma unroll
      for (int j = 0; j < HD; ++j) {
        float a = mb1[j];
        #pragma unroll
        for (int k = 0; k < HD; ++k) a = fmaf(h[d][k],     mW1[(k)      * HD + j], a);
        #pragma unroll
        for (int k = 0; k < HD; ++k) a = fmaf(h[1 - d][k], mW1[(16 + k) * HD + j], a);
        #pragma unroll
        for (int k = 0; k < HD; ++k) a = fmaf(ee[k],       mW1[(32 + k) * HD + j], a);
        t[j] = fmaxf(a, 0.0f);
      }
      outlin16(t, mW2, mb2, msg[d]);
    }

    #pragma unroll
    for (int d = 0; d < 2; ++d) {          // upd_d from pre-update h[d] and msg[d]
      float t[16];
      #pragma unroll
      for (int j = 0; j < HD; ++j) {
        float a = ub1[j];
        #pragma unroll
        for (int k = 0; k < HD; ++k) a = fmaf(h[d][k],   uW1[(k)      * HD + j], a);
        #pragma unroll
        for (int k = 0; k < HD; ++k) a = fmaf(msg[d][k], uW1[(16 + k) * HD + j], a);
        t[j] = fmaxf(a, 0.0f);
      }
      float u[16];
      outlin16(t, uW2, ub2, u);
      #pragma unroll
      for (int j = 0; j < HD; ++j) h[d][j] += u[j];   // upd_d reads only h[d]; safe in-place
    }
  }

  // ---- classifier: mean over nodes, MLP(16 -> 16 -> 1) ----
  float g[16];
  #pragma unroll
  for (int j = 0; j < HD; ++j) g[j] = 0.5f * (h[0][j] + h[1][j]);
  float t[16];
  #pragma unroll
  for (int j = 0; j < HD; ++j) {
    float a = clsb1[j];
    #pragma unroll
    for (int k = 0; k < HD; ++k) a = fmaf(g[k], clsW1[k * HD + j], a);
    t[j] = fmaxf(a, 0.0f);
  }
  float a = clsb2[0];
  #pragma unroll
  for (int k = 0; k < HD; ++k) a = fmaf(t[k], clsW2[k], a);
  out[i] = a;
}

extern "C" void kernel_launch(void* const* d_in, const int* in_sizes, int n_in,
                              void* d_out, int out_size, void* d_ws, size_t ws_size,
                              hipStream_t stream) {
  const float* nf    = (const float*)d_in[0];
  const float* dist  = (const float*)d_in[1];
  const float* dz    = (const float*)d_in[2];
  const float* s2p   = (const float*)d_in[3];
  const float* neW1  = (const float*)d_in[4];
  const float* neb1  = (const float*)d_in[5];
  const float* neW2  = (const float*)d_in[6];
  const float* neb2  = (const float*)d_in[7];
  const float* eeW1  = (const float*)d_in[8];
  const float* eeb1  = (const float*)d_in[9];
  const float* eeW2  = (const float*)d_in[10];
  const float* eeb2  = (const float*)d_in[11];
  const float* msgW1 = (const float*)d_in[12];
  const float* msgb1 = (const float*)d_in[13];
  const float* msgW2 = (const float*)d_in[14];
  const float* msgb2 = (const float*)d_in[15];
  const float* updW1 = (const float*)d_in[16];
  const float* updb1 = (const float*)d_in[17];
  const float* updW2 = (const float*)d_in[18];
  const float* updb2 = (const float*)d_in[19];
  const float* clsW1 = (const float*)d_in[20];
  const float* clsb1 = (const float*)d_in[21];
  const float* clsW2 = (const float*)d_in[22];
  const float* clsb2 = (const float*)d_in[23];

  const int B = in_sizes[1];               // edge_distance_3d is (B,)
  const int block = 256;
  const int grid = (B + block - 1) / block;

  egnn_fwd<<<grid, block, 0, stream>>>(
      nf, dist, dz, s2p,
      neW1, neb1, neW2, neb2,
      eeW1, eeb1, eeW2, eeb2,
      msgW1, msgb1, msgW2, msgb2,
      updW1, updb1, updW2, updb2,
      clsW1, clsb1, clsW2, clsb2,
      (float*)d_out, B);
}

// Round 2
// 106.116 us; speedup vs baseline: 2.3661x; 2.3661x over previous
//
#include <hip/hip_runtime.h>
#include <hip/hip_bf16.h>

typedef __attribute__((ext_vector_type(8))) short    s8v;  // bf16x8 MFMA operand
typedef __attribute__((ext_vector_type(4))) float    f4v;  // fp32x4 MFMA C/D
typedef __attribute__((ext_vector_type(4))) unsigned u4v;

__device__ __forceinline__ unsigned short bfu(float x){
  union { __hip_bfloat16 h; unsigned short u; } cv;
  cv.h = __float2bfloat16(x);           // RNE; compiler fuses pairs into v_cvt_pk_bf16_f32
  return cv.u;
}
__device__ __forceinline__ unsigned pkbf(float lo, float hi){
  return (unsigned)bfu(lo) | ((unsigned)bfu(hi) << 16);
}
__device__ __forceinline__ s8v mkfrag(unsigned a, unsigned b, unsigned c_, unsigned d){
  u4v u = {a, b, c_, d};
  return __builtin_bit_cast(s8v, u);
}
__device__ __forceinline__ f4v MM(s8v a, s8v b, f4v acc){
  return __builtin_amdgcn_mfma_f32_16x16x32_bf16(a, b, acc, 0, 0, 0);
}

struct Pk { unsigned p0, p1; };
template<bool RELU>
__device__ __forceinline__ Pk mkpk(f4v d){
  float a = d[0], b = d[1], c_ = d[2], e = d[3];
  if (RELU){ a = fmaxf(a,0.f); b = fmaxf(b,0.f); c_ = fmaxf(c_,0.f); e = fmaxf(e,0.f); }
  Pk r; r.p0 = pkbf(a, b); r.p1 = pkbf(c_, e); return r;
}
// Gather the 4 B-frag regs this lane needs, assuming the source occupies its k-half.
// D-layout source: feature f lives at lane (f>>2)*16 + col, reg f&3.
// B-frag (16x16x32): lane l (g=l>>4) reg r holds k = 8g+2r, 8g+2r+1.
struct Gt { unsigned a0, a1, a2, a3; };
__device__ __forceinline__ Gt gat(Pk p, int s0, int s1){
  Gt t;
  t.a0 = (unsigned)__shfl((int)p.p0, s0, 64);
  t.a1 = (unsigned)__shfl((int)p.p1, s0, 64);
  t.a2 = (unsigned)__shfl((int)p.p0, s1, 64);
  t.a3 = (unsigned)__shfl((int)p.p1, s1, 64);
  return t;
}
__device__ __forceinline__ s8v fragCat(const Gt& x, const Gt& y, bool lo){
  // B = [S1 (k=0..15) ; S2 (k=16..31)]
  return mkfrag(lo?x.a0:y.a0, lo?x.a1:y.a1, lo?x.a2:y.a2, lo?x.a3:y.a3);
}
__device__ __forceinline__ s8v fragPad(const Gt& x, bool lo){
  // B = [S (k=0..15) ; 0]
  return mkfrag(lo?x.a0:0u, lo?x.a1:0u, lo?x.a2:0u, lo?x.a3:0u);
}
// A = W^T fragment: lane holds A[out=c][in=8g+j] = W[8g+j][c]; rows >= K are zero-padded.
__device__ __forceinline__ s8v loadWT(const float* __restrict__ W, int K, int c, int g){
  int k = 8*g;
  unsigned u0 = pkbf(k+0<K ? W[(k+0)*16+c] : 0.f, k+1<K ? W[(k+1)*16+c] : 0.f);
  unsigned u1 = pkbf(k+2<K ? W[(k+2)*16+c] : 0.f, k+3<K ? W[(k+3)*16+c] : 0.f);
  unsigned u2 = pkbf(k+4<K ? W[(k+4)*16+c] : 0.f, k+5<K ? W[(k+5)*16+c] : 0.f);
  unsigned u3 = pkbf(k+6<K ? W[(k+6)*16+c] : 0.f, k+7<K ? W[(k+7)*16+c] : 0.f);
  return mkfrag(u0, u1, u2, u3);
}
// Bias as MFMA C-init: C[row=4g+r][col] = b[4g+r]  (free bias add)
__device__ __forceinline__ f4v ldb(const float* __restrict__ b, int g){
  f4v v; v[0] = b[4*g+0]; v[1] = b[4*g+1]; v[2] = b[4*g+2]; v[3] = b[4*g+3];
  return v;
}

__global__ void __launch_bounds__(256) egnn_mfma(
    const float* __restrict__ nf,   const float* __restrict__ dist,
    const float* __restrict__ dz,   const float* __restrict__ s2p,
    const float* __restrict__ neW1, const float* __restrict__ neb1,
    const float* __restrict__ neW2, const float* __restrict__ neb2,
    const float* __restrict__ eeW1, const float* __restrict__ eeb1,
    const float* __restrict__ eeW2, const float* __restrict__ eeb2,
    const float* __restrict__ msgW1, const float* __restrict__ msgb1,
    const float* __restrict__ msgW2, const float* __restrict__ msgb2,
    const float* __restrict__ updW1, const float* __restrict__ updb1,
    const float* __restrict__ updW2, const float* __restrict__ updb2,
    const float* __restrict__ clsW1, const float* __restrict__ clsb1,
    const float* __restrict__ clsW2, const float* __restrict__ clsb2,
    float* __restrict__ out, int B, int ngroups, int nwaves)
{
  const int lane = threadIdx.x & 63;
  const int c  = lane & 15;          // edge column
  const int g  = lane >> 4;          // k-slice group
  const bool lo = lane < 32;
  const int s0 = c + 32*(g & 1);     // gather sources for D->B redistribution
  const int s1 = s0 + 16;
  const int gwave = blockIdx.x * (blockDim.x >> 6) + (threadIdx.x >> 6);

  // ---- one-time per-wave weight fragments (A = W^T) and fp32 bias C-inits ----
  s8v aNe1 = loadWT(neW1, 2, c, g);
  s8v aNe2 = loadWT(neW2, 16, c, g);
  s8v aEe1 = loadWT(eeW1, 3, c, g);
  s8v aEe2 = loadWT(eeW2, 16, c, g);
  s8v aCl  = loadWT(clsW1, 16, c, g);
  s8v aM0[2], aM1[2], aM2[2], aU1[2], aU2[2];
  f4v bM1[2], bM2[2], bU1[2], bU2[2];
  #pragma unroll
  for (int l = 0; l < 2; ++l){
    aM0[l] = loadWT(msgW1 + l*768,       32, c, g);  // concat rows 0..31
    aM1[l] = loadWT(msgW1 + l*768 + 512, 16, c, g);  // concat rows 32..47 (ee)
    aM2[l] = loadWT(msgW2 + l*256, 16, c, g);
    aU1[l] = loadWT(updW1 + l*512, 32, c, g);
    aU2[l] = loadWT(updW2 + l*256, 16, c, g);
    bM1[l] = ldb(msgb1 + l*16, g);
    bM2[l] = ldb(msgb2 + l*16, g);
    bU1[l] = ldb(updb1 + l*16, g);
    bU2[l] = ldb(updb2 + l*16, g);
  }
  f4v bNe1 = ldb(neb1,g), bNe2 = ldb(neb2,g), bEe1 = ldb(eeb1,g), bEe2 = ldb(eeb2,g), bCl1 = ldb(clsb1,g);
  const float w2a = clsW2[4*g+0], w2b = clsW2[4*g+1], w2c = clsW2[4*g+2], w2d = clsW2[4*g+3];
  const float cb2 = clsb2[0];

  for (int grp = gwave; grp < ngroups; grp += nwaves){
    const int e0 = grp * 16;
    const int e  = min(e0 + c, B - 1);
    const float4 nfe = *reinterpret_cast<const float4*>(nf + (size_t)e * 4);
    const float di = dist[e], zz = dz[e], sp = s2p[e];

    // ---- embeddings (activations live as X^T: col=edge, row=feature) ----
    f4v h0, h1, ee;
    {
      s8v b0 = mkfrag(g==0 ? pkbf(nfe.x, nfe.y) : 0u, 0u, 0u, 0u);
      s8v b1 = mkfrag(g==0 ? pkbf(nfe.z, nfe.w) : 0u, 0u, 0u, 0u);
      f4v t0 = MM(aNe1, b0, bNe1);
      f4v t1 = MM(aNe1, b1, bNe1);
      Gt g0 = gat(mkpk<true>(t0), s0, s1);
      Gt g1 = gat(mkpk<true>(t1), s0, s1);
      h0 = MM(aNe2, fragPad(g0, lo), bNe2);
      h1 = MM(aNe2, fragPad(g1, lo), bNe2);
      s8v be = mkfrag(g==0 ? pkbf(di, zz) : 0u, g==0 ? pkbf(sp, 0.f) : 0u, 0u, 0u);
      f4v te = MM(aEe1, be, bEe1);
      Gt ge = gat(mkpk<true>(te), s0, s1);
      ee = MM(aEe2, fragPad(ge, lo), bEe2);
    }

    // ---- message-passing layers (h state stays fp32) ----
    #pragma unroll
    for (int l = 0; l < 2; ++l){
      Gt gh0 = gat(mkpk<false>(h0), s0, s1);
      Gt gh1 = gat(mkpk<false>(h1), s0, s1);
      Gt ge  = gat(mkpk<false>(ee), s0, s1);
      // msg_01
      f4v m0 = MM(aM0[l], fragCat(gh0, gh1, lo), bM1[l]);
      m0 = MM(aM1[l], fragPad(ge, lo), m0);
      Gt gm0 = gat(mkpk<true>(m0), s0, s1);
      f4v msg0 = MM(aM2[l], fragPad(gm0, lo), bM2[l]);
      // msg_10
      f4v m1 = MM(aM0[l], fragCat(gh1, gh0, lo), bM1[l]);
      m1 = MM(aM1[l], fragPad(ge, lo), m1);
      Gt gm1 = gat(mkpk<true>(m1), s0, s1);
      f4v msg1 = MM(aM2[l], fragPad(gm1, lo), bM2[l]);
      // upd_0
      Gt gs0 = gat(mkpk<false>(msg0), s0, s1);
      f4v u0 = MM(aU1[l], fragCat(gh0, gs0, lo), bU1[l]);
      Gt gu0 = gat(mkpk<true>(u0), s0, s1);
      f4v w0 = MM(aU2[l], fragPad(gu0, lo), bU2[l]);
      // upd_1
      Gt gs1 = gat(mkpk<false>(msg1), s0, s1);
      f4v u1 = MM(aU1[l], fragCat(gh1, gs1, lo), bU1[l]);
      Gt gu1 = gat(mkpk<true>(u1), s0, s1);
      f4v w1 = MM(aU2[l], fragPad(gu1, lo), bU2[l]);
      h0 = h0 + w0;
      h1 = h1 + w1;
    }

    // ---- classifier ----
    f4v gb = 0.5f * (h0 + h1);
    Gt gg = gat(mkpk<false>(gb), s0, s1);
    f4v tc = MM(aCl, fragPad(gg, lo), bCl1);
    float part = fmaxf(tc[0],0.f)*w2a + fmaxf(tc[1],0.f)*w2b
               + fmaxf(tc[2],0.f)*w2c + fmaxf(tc[3],0.f)*w2d;
    part += __shfl_xor(part, 16, 64);
    part += __shfl_xor(part, 32, 64);
    if (lane < 16 && (e0 + c) < B) out[e0 + c] = part + cb2;
  }
}

extern "C" void kernel_launch(void* const* d_in, const int* in_sizes, int n_in,
                              void* d_out, int out_size, void* d_ws, size_t ws_size,
                              hipStream_t stream) {
  const float* nf    = (const float*)d_in[0];
  const float* dist  = (const float*)d_in[1];
  const float* dz    = (const float*)d_in[2];
  const float* s2p   = (const float*)d_in[3];
  const float* neW1  = (const float*)d_in[4];
  const float* neb1  = (const float*)d_in[5];
  const float* neW2  = (const float*)d_in[6];
  const float* neb2  = (const float*)d_in[7];
  const float* eeW1  = (const float*)d_in[8];
  const float* eeb1  = (const float*)d_in[9];
  const float* eeW2  = (const float*)d_in[10];
  const float* eeb2  = (const float*)d_in[11];
  const float* msgW1 = (const float*)d_in[12];
  const float* msgb1 = (const float*)d_in[13];
  const float* msgW2 = (const float*)d_in[14];
  const float* msgb2 = (const float*)d_in[15];
  const float* updW1 = (const float*)d_in[16];
  const float* updb1 = (const float*)d_in[17];
  const float* updW2 = (const float*)d_in[18];
  const float* updb2 = (const float*)d_in[19];
  const float* clsW1 = (const float*)d_in[20];
  const float* clsb1 = (const float*)d_in[21];
  const float* clsW2 = (const float*)d_in[22];
  const float* clsb2 = (const float*)d_in[23];

  const int B = in_sizes[1];
  const int ngroups = (B + 15) / 16;
  int blocks = 1024;                          // 4096 waves, 16 groups each at B=1M
  const int wpb = 256 / 64;
  if (blocks * wpb > ngroups) blocks = (ngroups + wpb - 1) / wpb;
  const int nwaves = blocks * wpb;

  egnn_mfma<<<blocks, 256, 0, stream>>>(
      nf, dist, dz, s2p,
      neW1, neb1, neW2, neb2,
      eeW1, eeb1, eeW2, eeb2,
      msgW1, msgb1, msgW2, msgb2,
      updW1, updb1, updW2, updb2,
      clsW1, clsb1, clsW2, clsb2,
      (float*)d_out, B, ngroups, nwaves);
}

// Round 4
// 98.404 us; speedup vs baseline: 2.5515x; 1.0784x over previous
//
#include <hip/hip_runtime.h>
#include <hip/hip_bf16.h>

typedef __attribute__((ext_vector_type(8))) short    s8v;  // bf16x8 MFMA operand
typedef __attribute__((ext_vector_type(4))) float    f4v;  // fp32x4 MFMA C/D
typedef __attribute__((ext_vector_type(4))) unsigned u4v;

__device__ __forceinline__ unsigned short bfu(float x){
  union { __hip_bfloat16 h; unsigned short u; } cv;
  cv.h = __float2bfloat16(x);
  return cv.u;
}
__device__ __forceinline__ unsigned pkbf(float lo, float hi){
  return (unsigned)bfu(lo) | ((unsigned)bfu(hi) << 16);
}
__device__ __forceinline__ s8v mkfrag(unsigned a, unsigned b, unsigned c_, unsigned d){
  u4v u = {a, b, c_, d};
  return __builtin_bit_cast(s8v, u);
}
__device__ __forceinline__ f4v MM(s8v a, s8v b, f4v acc){
  return __builtin_amdgcn_mfma_f32_16x16x32_bf16(a, b, acc, 0, 0, 0);
}

struct Pk { unsigned p0, p1; };
template<bool RELU>
__device__ __forceinline__ Pk mkpk(f4v d){
  float a = d[0], b = d[1], c_ = d[2], e = d[3];
  if (RELU){ a = fmaxf(a,0.f); b = fmaxf(b,0.f); c_ = fmaxf(c_,0.f); e = fmaxf(e,0.f); }
  Pk r; r.p0 = pkbf(a, b); r.p1 = pkbf(c_, e); return r;
}

// gfx950 permlane swaps (VALU, no LDS pipe). Verified direction:
//   pl32(A,B): A.rows[2:3] <-> B.rows[0:1]   (A-high <-> B-low; row = 16 lanes)
//   pl16(A,B): A.rows{1,3} <-> B.rows{0,2}   (A-odd  <-> B-even)
__device__ __forceinline__ void pl32(unsigned &a, unsigned &b){
  asm("v_permlane32_swap_b32 %0, %1" : "+v"(a), "+v"(b));
}
__device__ __forceinline__ void pl16(unsigned &a, unsigned &b){
  asm("v_permlane16_swap_b32 %0, %1" : "+v"(a), "+v"(b));
}

// Transpose packed D-layout (quarter q holds rows 4q..4q+3 of col c; p0 =
// rows 4q,4q+1; p1 = rows 4q+2,4q+3) into the next MFMA's B-fragment,
// NATURAL k-order: B = [x as k=0..15 ; y as k=16..31].
//   X=[X0,X1,X2,X3], Y=[Y0..Y3]:  pl32(X,Y) -> X=[X0,X1,Y0,Y1], Y=[X2,X3,Y2,Y3]
//   then pl16(X,Y) -> X=[X0,X2,Y0,Y2]=b0, Y=[X1,X3,Y1,Y3]=b2.
// Pass-by-value: callers' Pk values survive.
__device__ __forceinline__ s8v chainCat(Pk x, Pk y){
  pl32(x.p0, y.p0);
  pl16(x.p0, y.p0);
  pl32(x.p1, y.p1);
  pl16(x.p1, y.p1);
  return mkfrag(x.p0, x.p1, y.p0, y.p1);   // b0, b1, b2, b3
}
// [S ; S] duplicate — hi k-half multiplied by zero A-rows for K=16 consumers
// (values are finite, so 0*x == 0; no NaN risk).
__device__ __forceinline__ s8v chainDup(Pk x){ return chainCat(x, x); }

// A = W^T fragment: lane holds A[out=c][in=8g+j] = W[8g+j][c]; rows >= K zero.
__device__ __forceinline__ s8v loadWT(const float* __restrict__ W, int K, int c, int g){
  int k = 8*g;
  unsigned u0 = pkbf(k+0<K ? W[(k+0)*16+c] : 0.f, k+1<K ? W[(k+1)*16+c] : 0.f);
  unsigned u1 = pkbf(k+2<K ? W[(k+2)*16+c] : 0.f, k+3<K ? W[(k+3)*16+c] : 0.f);
  unsigned u2 = pkbf(k+4<K ? W[(k+4)*16+c] : 0.f, k+5<K ? W[(k+5)*16+c] : 0.f);
  unsigned u3 = pkbf(k+6<K ? W[(k+6)*16+c] : 0.f, k+7<K ? W[(k+7)*16+c] : 0.f);
  return mkfrag(u0, u1, u2, u3);
}
// Bias as MFMA C-init: C[row=4g+r][col] = b[4g+r]
__device__ __forceinline__ f4v ldb(const float* __restrict__ b, int g){
  f4v v; v[0] = b[4*g+0]; v[1] = b[4*g+1]; v[2] = b[4*g+2]; v[3] = b[4*g+3];
  return v;
}

__global__ void __launch_bounds__(256) egnn_pl(
    const float* __restrict__ nf,   const float* __restrict__ dist,
    const float* __restrict__ dz,   const float* __restrict__ s2p,
    const float* __restrict__ neW1, const float* __restrict__ neb1,
    const float* __restrict__ neW2, const float* __restrict__ neb2,
    const float* __restrict__ eeW1, const float* __restrict__ eeb1,
    const float* __restrict__ eeW2, const float* __restrict__ eeb2,
    const float* __restrict__ msgW1, const float* __restrict__ msgb1,
    const float* __restrict__ msgW2, const float* __restrict__ msgb2,
    const float* __restrict__ updW1, const float* __restrict__ updb1,
    const float* __restrict__ updW2, const float* __restrict__ updb2,
    const float* __restrict__ clsW1, const float* __restrict__ clsb1,
    const float* __restrict__ clsW2, const float* __restrict__ clsb2,
    float* __restrict__ out, int B, int ngroups, int nwaves)
{
  const int lane = threadIdx.x & 63;
  const int c = lane & 15;
  const int g = lane >> 4;
  const int gwave = blockIdx.x * (blockDim.x >> 6) + (threadIdx.x >> 6);

  // ---- per-wave weight fragments & biases (natural k-order everywhere) ----
  s8v aNe1 = loadWT(neW1, 2, c, g);
  s8v aNe2 = loadWT(neW2, 16, c, g);
  s8v aEe1 = loadWT(eeW1, 3, c, g);
  s8v aEe2 = loadWT(eeW2, 16, c, g);
  s8v aCl  = loadWT(clsW1, 16, c, g);
  s8v aM0[2], aM1[2], aM2[2], aU1[2], aU2[2];
  f4v bM1[2], bM2[2], bU1[2], bU2[2];
  #pragma unroll
  for (int l = 0; l < 2; ++l){
    aM0[l] = loadWT(msgW1 + l*768,       32, c, g);  // concat rows 0..31
    aM1[l] = loadWT(msgW1 + l*768 + 512, 16, c, g);  // concat rows 32..47 (ee)
    aM2[l] = loadWT(msgW2 + l*256, 16, c, g);
    aU1[l] = loadWT(updW1 + l*512, 32, c, g);        // rows 0..15 h, 16..31 msg
    aU2[l] = loadWT(updW2 + l*256, 16, c, g);
    bM1[l] = ldb(msgb1 + l*16, g);
    bM2[l] = ldb(msgb2 + l*16, g);
    bU1[l] = ldb(updb1 + l*16, g);
    bU2[l] = ldb(updb2 + l*16, g);
  }
  f4v bNe1 = ldb(neb1,g), bNe2 = ldb(neb2,g), bEe1 = ldb(eeb1,g), bEe2 = ldb(eeb2,g), bCl1 = ldb(clsb1,g);
  const float w2a = clsW2[4*g+0], w2b = clsW2[4*g+1], w2c = clsW2[4*g+2], w2d = clsW2[4*g+3];
  const float cb2 = clsb2[0];

  // ---- software-prefetched group loop ----
  int grp = gwave;
  float4 nfe = {0,0,0,0}; float di = 0, zz = 0, sp = 0;
  if (grp < ngroups){
    int e = min(grp*16 + c, B-1);
    nfe = *reinterpret_cast<const float4*>(nf + (size_t)e * 4);
    di = dist[e]; zz = dz[e]; sp = s2p[e];
  }

  #pragma unroll 1
  for (; grp < ngroups; grp += nwaves){
    const int e0 = grp * 16;
    float4 nfeN = nfe; float diN = di, zzN = zz, spN = sp;
    const int nxt = grp + nwaves;
    if (nxt < ngroups){
      int e = min(nxt*16 + c, B-1);
      nfeN = *reinterpret_cast<const float4*>(nf + (size_t)e * 4);
      diN = dist[e]; zzN = dz[e]; spN = s2p[e];
    }

    // ---- embeddings (activations live as X^T: col=edge, row=feature) ----
    s8v b0 = mkfrag(g==0 ? pkbf(nfe.x, nfe.y) : 0u, 0u, 0u, 0u);
    s8v b1 = mkfrag(g==0 ? pkbf(nfe.z, nfe.w) : 0u, 0u, 0u, 0u);
    s8v be = mkfrag(g==0 ? pkbf(di, zz) : 0u, g==0 ? pkbf(sp, 0.f) : 0u, 0u, 0u);
    f4v t0 = MM(aNe1, b0, bNe1);
    f4v t1 = MM(aNe1, b1, bNe1);
    f4v te = MM(aEe1, be, bEe1);
    f4v h0 = MM(aNe2, chainDup(mkpk<true>(t0)), bNe2);
    f4v h1 = MM(aNe2, chainDup(mkpk<true>(t1)), bNe2);
    f4v ee = MM(aEe2, chainDup(mkpk<true>(te)), bEe2);
    const s8v eeF = chainDup(mkpk<false>(ee));   // loop-invariant across layers

    // ---- message-passing layers (h state fp32) ----
    #pragma unroll
    for (int l = 0; l < 2; ++l){
      Pk ph0 = mkpk<false>(h0), ph1 = mkpk<false>(h1);
      // msg_d = W[0:16]*n_d + W[16:32]*n_other + W[32:48]*ee (+b)
      f4v m0 = MM(aM0[l], chainCat(ph0, ph1), MM(aM1[l], eeF, bM1[l]));
      f4v m1 = MM(aM0[l], chainCat(ph1, ph0), MM(aM1[l], eeF, bM1[l]));
      f4v g0 = MM(aM2[l], chainDup(mkpk<true>(m0)), bM2[l]);
      f4v g1 = MM(aM2[l], chainDup(mkpk<true>(m1)), bM2[l]);
      // upd_d: concat [h_d ; msg_d]
      f4v u0 = MM(aU1[l], chainCat(ph0, mkpk<false>(g0)), bU1[l]);
      f4v u1 = MM(aU1[l], chainCat(ph1, mkpk<false>(g1)), bU1[l]);
      h0 = h0 + MM(aU2[l], chainDup(mkpk<true>(u0)), bU2[l]);
      h1 = h1 + MM(aU2[l], chainDup(mkpk<true>(u1)), bU2[l]);
    }

    // ---- classifier ----
    f4v gb = 0.5f * (h0 + h1);
    f4v tc = MM(aCl, chainDup(mkpk<false>(gb)), bCl1);
    float part = fmaxf(tc[0],0.f)*w2a + fmaxf(tc[1],0.f)*w2b
               + fmaxf(tc[2],0.f)*w2c + fmaxf(tc[3],0.f)*w2d;
    // reduce over the 4 quarters via permlane (direction-agnostic):
    unsigned pu = __builtin_bit_cast(unsigned, part), pv = pu;
    pl16(pu, pv);
    part = __builtin_bit_cast(float, pu) + __builtin_bit_cast(float, pv);
    pu = __builtin_bit_cast(unsigned, part); pv = pu;
    pl32(pu, pv);
    part = __builtin_bit_cast(float, pu) + __builtin_bit_cast(float, pv);
    if (lane < 16 && (e0 + c) < B) out[e0 + c] = part + cb2;

    nfe = nfeN; di = diN; zz = zzN; sp = spN;
  }
}

extern "C" void kernel_launch(void* const* d_in, const int* in_sizes, int n_in,
                              void* d_out, int out_size, void* d_ws, size_t ws_size,
                              hipStream_t stream) {
  const float* nf    = (const float*)d_in[0];
  const float* dist  = (const float*)d_in[1];
  const float* dz    = (const float*)d_in[2];
  const float* s2p   = (const float*)d_in[3];
  const float* neW1  = (const float*)d_in[4];
  const float* neb1  = (const float*)d_in[5];
  const float* neW2  = (const float*)d_in[6];
  const float* neb2  = (const float*)d_in[7];
  const float* eeW1  = (const float*)d_in[8];
  const float* eeb1  = (const float*)d_in[9];
  const float* eeW2  = (const float*)d_in[10];
  const float* eeb2  = (const float*)d_in[11];
  const float* msgW1 = (const float*)d_in[12];
  const float* msgb1 = (const float*)d_in[13];
  const float* msgW2 = (const float*)d_in[14];
  const float* msgb2 = (const float*)d_in[15];
  const float* updW1 = (const float*)d_in[16];
  const float* updb1 = (const float*)d_in[17];
  const float* updW2 = (const float*)d_in[18];
  const float* updb2 = (const float*)d_in[19];
  const float* clsW1 = (const float*)d_in[20];
  const float* clsb1 = (const float*)d_in[21];
  const float* clsW2 = (const float*)d_in[22];
  const float* clsb2 = (const float*)d_in[23];

  const int B = in_sizes[1];
  const int ngroups = (B + 15) / 16;
  int blocks = 1024;
  const int wpb = 256 / 64;
  if (blocks * wpb > ngroups) blocks = (ngroups + wpb - 1) / wpb;
  const int nwaves = blocks * wpb;

  egnn_pl<<<blocks, 256, 0, stream>>>(
      nf, dist, dz, s2p,
      neW1, neb1, neW2, neb2,
      eeW1, eeb1, eeW2, eeb2,
      msgW1, msgb1, msgW2, msgb2,
      updW1, updb1, updW2, updb2,
      clsW1, clsb1, clsW2, clsb2,
      (float*)d_out, B, ngroups, nwaves);
}

// Round 5
// 64.181 us; speedup vs baseline: 3.9120x; 1.5332x over previous
//
#include <hip/hip_runtime.h>
#include <hip/hip_bf16.h>

typedef __attribute__((ext_vector_type(8))) short    s8v;  // bf16x8 MFMA operand
typedef __attribute__((ext_vector_type(4))) float    f4v;  // fp32x4 MFMA C/D
typedef __attribute__((ext_vector_type(4))) unsigned u4v;

__device__ __forceinline__ unsigned short bfu(float x){
  union { __hip_bfloat16 h; unsigned short u; } cv;
  cv.h = __float2bfloat16(x);
  return cv.u;
}
__device__ __forceinline__ unsigned pkbf(float lo, float hi){
  return (unsigned)bfu(lo) | ((unsigned)bfu(hi) << 16);
}
__device__ __forceinline__ s8v mkfrag(unsigned a, unsigned b, unsigned c_, unsigned d){
  u4v u = {a, b, c_, d};
  return __builtin_bit_cast(s8v, u);
}
__device__ __forceinline__ f4v MM(s8v a, s8v b, f4v acc){
  return __builtin_amdgcn_mfma_f32_16x16x32_bf16(a, b, acc, 0, 0, 0);
}

// Packed D-quad: p0 = (row 4g, 4g+1), p1 = (row 4g+2, 4g+3) at col c.
struct Pk { unsigned p0, p1; };
template<bool RELU>
__device__ __forceinline__ Pk mkpk(f4v d){
  float a = d[0], b = d[1], c_ = d[2], e = d[3];
  if (RELU){ a = fmaxf(a,0.f); b = fmaxf(b,0.f); c_ = fmaxf(c_,0.f); e = fmaxf(e,0.f); }
  Pk r; r.p0 = pkbf(a, b); r.p1 = pkbf(c_, e); return r;
}

// ZERO-SHUFFLE CHAINING: B-frag slot (reg j, row g) covers k=8g+2j,+1.
// Feeding (p0,p1,*,*) directly puts feature f=4g+r at k=8g+r (r<4).  MFMA sums
// over k, so we load A with the SAME row permutation and no data movement is
// needed between stages:
//   K<=16 consumer (B = p0,p1,0,0):  A[c][8g+r] = r<4 && 4g+r<K ? W[4g+r][c] : 0
//   K=32 concat  (B = xp0,xp1,yp0,yp1): r<4 -> W[4g+r][c], r>=4 -> W[16+4g+r-4][c]
__device__ __forceinline__ s8v bfragK16(Pk x){ return mkfrag(x.p0, x.p1, 0u, 0u); }
__device__ __forceinline__ s8v bfragCat(Pk x, Pk y){ return mkfrag(x.p0, x.p1, y.p0, y.p1); }

__device__ __forceinline__ s8v loadA16(const float* __restrict__ W, int K, int c, int g,
                                       float scale = 1.0f){
  int r0 = 4*g;
  unsigned u0 = pkbf(r0+0<K ? W[(r0+0)*16+c]*scale : 0.f, r0+1<K ? W[(r0+1)*16+c]*scale : 0.f);
  unsigned u1 = pkbf(r0+2<K ? W[(r0+2)*16+c]*scale : 0.f, r0+3<K ? W[(r0+3)*16+c]*scale : 0.f);
  return mkfrag(u0, u1, 0u, 0u);
}
__device__ __forceinline__ s8v loadA32(const float* __restrict__ W, int c, int g){
  int r0 = 4*g;
  unsigned u0 = pkbf(W[(r0+0)*16+c],      W[(r0+1)*16+c]);
  unsigned u1 = pkbf(W[(r0+2)*16+c],      W[(r0+3)*16+c]);
  unsigned u2 = pkbf(W[(16+r0+0)*16+c],   W[(16+r0+1)*16+c]);
  unsigned u3 = pkbf(W[(16+r0+2)*16+c],   W[(16+r0+3)*16+c]);
  return mkfrag(u0, u1, u2, u3);
}
// Bias as MFMA C-init: C[row=4g+r][col] = b[4g+r]
__device__ __forceinline__ f4v ldb(const float* __restrict__ b, int g){
  f4v v; v[0] = b[4*g+0]; v[1] = b[4*g+1]; v[2] = b[4*g+2]; v[3] = b[4*g+3];
  return v;
}

// permlane swaps for the final 4-quarter reduction only (VALU, no LDS).
__device__ __forceinline__ void pl32(unsigned &a, unsigned &b){
  asm("v_permlane32_swap_b32 %0, %1" : "+v"(a), "+v"(b));
}
__device__ __forceinline__ void pl16(unsigned &a, unsigned &b){
  asm("v_permlane16_swap_b32 %0, %1" : "+v"(a), "+v"(b));
}

__global__ void __launch_bounds__(256) egnn_zs(
    const float* __restrict__ nf,   const float* __restrict__ dist,
    const float* __restrict__ dz,   const float* __restrict__ s2p,
    const float* __restrict__ neW1, const float* __restrict__ neb1,
    const float* __restrict__ neW2, const float* __restrict__ neb2,
    const float* __restrict__ eeW1, const float* __restrict__ eeb1,
    const float* __restrict__ eeW2, const float* __restrict__ eeb2,
    const float* __restrict__ msgW1, const float* __restrict__ msgb1,
    const float* __restrict__ msgW2, const float* __restrict__ msgb2,
    const float* __restrict__ updW1, const float* __restrict__ updb1,
    const float* __restrict__ updW2, const float* __restrict__ updb2,
    const float* __restrict__ clsW1, const float* __restrict__ clsb1,
    const float* __restrict__ clsW2, const float* __restrict__ clsb2,
    float* __restrict__ out, int B, int ngroups, int nwaves)
{
  const int lane = threadIdx.x & 63;
  const int c = lane & 15;
  const int g = lane >> 4;
  const int gwave = blockIdx.x * (blockDim.x >> 6) + (threadIdx.x >> 6);

  // ---- per-wave weight fragments (permuted rows) & bias C-inits ----
  s8v aNe1 = loadA16(neW1, 2, c, g);
  s8v aNe2 = loadA16(neW2, 16, c, g);
  s8v aEe1 = loadA16(eeW1, 3, c, g);
  s8v aEe2 = loadA16(eeW2, 16, c, g);
  s8v aCl  = loadA16(clsW1, 16, c, g, 0.5f);   // fold the node-mean 0.5
  s8v aM0[2], aM1[2], aM2[2], aU1[2], aU2[2];
  f4v bM1[2], bM2[2], bU1[2], bU2[2];
  #pragma unroll
  for (int l = 0; l < 2; ++l){
    aM0[l] = loadA32(msgW1 + l*768, c, g);            // concat rows 0..31
    aM1[l] = loadA16(msgW1 + l*768 + 512, 16, c, g);  // rows 32..47 (ee)
    aM2[l] = loadA16(msgW2 + l*256, 16, c, g);
    aU1[l] = loadA32(updW1 + l*512, c, g);            // rows 0..15 h, 16..31 msg
    aU2[l] = loadA16(updW2 + l*256, 16, c, g);
    bM1[l] = ldb(msgb1 + l*16, g);
    bM2[l] = ldb(msgb2 + l*16, g);
    bU1[l] = ldb(updb1 + l*16, g);
    bU2[l] = ldb(updb2 + l*16, g);
  }
  f4v bNe1 = ldb(neb1,g), bNe2 = ldb(neb2,g), bEe1 = ldb(eeb1,g), bEe2 = ldb(eeb2,g), bCl1 = ldb(clsb1,g);
  const float w2a = clsW2[4*g+0], w2b = clsW2[4*g+1], w2c = clsW2[4*g+2], w2d = clsW2[4*g+3];
  const float cb2 = clsb2[0];

  // ---- software-prefetched group loop ----
  int grp = gwave;
  float4 nfe = {0,0,0,0}; float di = 0, zz = 0, sp = 0;
  if (grp < ngroups){
    int e = min(grp*16 + c, B-1);
    nfe = *reinterpret_cast<const float4*>(nf + (size_t)e * 4);
    di = dist[e]; zz = dz[e]; sp = s2p[e];
  }

  #pragma unroll 1
  for (; grp < ngroups; grp += nwaves){
    const int e0 = grp * 16;
    float4 nfeN = nfe; float diN = di, zzN = zz, spN = sp;
    const int nxt = grp + nwaves;
    if (nxt < ngroups){
      int e = min(nxt*16 + c, B-1);
      nfeN = *reinterpret_cast<const float4*>(nf + (size_t)e * 4);
      diN = dist[e]; zzN = dz[e]; spN = s2p[e];
    }

    // ---- embeddings (inputs at k=0..3, g==0 slots; A rows 0..3 natural) ----
    s8v b0 = mkfrag(g==0 ? pkbf(nfe.x, nfe.y) : 0u, 0u, 0u, 0u);
    s8v b1 = mkfrag(g==0 ? pkbf(nfe.z, nfe.w) : 0u, 0u, 0u, 0u);
    s8v be = mkfrag(g==0 ? pkbf(di, zz) : 0u, g==0 ? pkbf(sp, 0.f) : 0u, 0u, 0u);
    f4v t0 = MM(aNe1, b0, bNe1);
    f4v t1 = MM(aNe1, b1, bNe1);
    f4v te = MM(aEe1, be, bEe1);
    f4v h0 = MM(aNe2, bfragK16(mkpk<true>(t0)), bNe2);
    f4v h1 = MM(aNe2, bfragK16(mkpk<true>(t1)), bNe2);
    f4v ee = MM(aEe2, bfragK16(mkpk<true>(te)), bEe2);
    const s8v eeB = bfragK16(mkpk<false>(ee));   // reused by both layers

    // ---- message-passing layers (h state fp32) ----
    #pragma unroll
    for (int l = 0; l < 2; ++l){
      Pk ph0 = mkpk<false>(h0), ph1 = mkpk<false>(h1);
      f4v eC = MM(aM1[l], eeB, bM1[l]);            // shared ee contribution
      f4v m0 = MM(aM0[l], bfragCat(ph0, ph1), eC); // msg_01
      f4v m1 = MM(aM0[l], bfragCat(ph1, ph0), eC); // msg_10
      f4v g0 = MM(aM2[l], bfragK16(mkpk<true>(m0)), bM2[l]);
      f4v g1 = MM(aM2[l], bfragK16(mkpk<true>(m1)), bM2[l]);
      f4v u0 = MM(aU1[l], bfragCat(ph0, mkpk<false>(g0)), bU1[l]);
      f4v u1 = MM(aU1[l], bfragCat(ph1, mkpk<false>(g1)), bU1[l]);
      h0 = h0 + MM(aU2[l], bfragK16(mkpk<true>(u0)), bU2[l]);
      h1 = h1 + MM(aU2[l], bfragK16(mkpk<true>(u1)), bU2[l]);
    }

    // ---- classifier (0.5 pre-folded into aCl) ----
    f4v gb = h0 + h1;
    f4v tc = MM(aCl, bfragK16(mkpk<false>(gb)), bCl1);
    float part = fmaxf(tc[0],0.f)*w2a + fmaxf(tc[1],0.f)*w2b
               + fmaxf(tc[2],0.f)*w2c + fmaxf(tc[3],0.f)*w2d;
    // reduce over the 4 quarters via permlane
    unsigned pu = __builtin_bit_cast(unsigned, part), pv = pu;
    pl16(pu, pv);
    part = __builtin_bit_cast(float, pu) + __builtin_bit_cast(float, pv);
    pu = __builtin_bit_cast(unsigned, part); pv = pu;
    pl32(pu, pv);
    part = __builtin_bit_cast(float, pu) + __builtin_bit_cast(float, pv);
    if (lane < 16 && (e0 + c) < B) out[e0 + c] = part + cb2;

    nfe = nfeN; di = diN; zz = zzN; sp = spN;
  }
}

extern "C" void kernel_launch(void* const* d_in, const int* in_sizes, int n_in,
                              void* d_out, int out_size, void* d_ws, size_t ws_size,
                              hipStream_t stream) {
  const float* nf    = (const float*)d_in[0];
  const float* dist  = (const float*)d_in[1];
  const float* dz    = (const float*)d_in[2];
  const float* s2p   = (const float*)d_in[3];
  const float* neW1  = (const float*)d_in[4];
  const float* neb1  = (const float*)d_in[5];
  const float* neW2  = (const float*)d_in[6];
  const float* neb2  = (const float*)d_in[7];
  const float* eeW1  = (const float*)d_in[8];
  const float* eeb1  = (const float*)d_in[9];
  const float* eeW2  = (const float*)d_in[10];
  const float* eeb2  = (const float*)d_in[11];
  const float* msgW1 = (const float*)d_in[12];
  const float* msgb1 = (const float*)d_in[13];
  const float* msgW2 = (const float*)d_in[14];
  const float* msgb2 = (const float*)d_in[15];
  const float* updW1 = (const float*)d_in[16];
  const float* updb1 = (const float*)d_in[17];
  const float* updW2 = (const float*)d_in[18];
  const float* updb2 = (const float*)d_in[19];
  const float* clsW1 = (const float*)d_in[20];
  const float* clsb1 = (const float*)d_in[21];
  const float* clsW2 = (const float*)d_in[22];
  const float* clsb2 = (const float*)d_in[23];

  const int B = in_sizes[1];
  const int ngroups = (B + 15) / 16;
  int blocks = 1024;
  const int wpb = 256 / 64;
  if (blocks * wpb > ngroups) blocks = (ngroups + wpb - 1) / wpb;
  const int nwaves = blocks * wpb;

  egnn_zs<<<blocks, 256, 0, stream>>>(
      nf, dist, dz, s2p,
      neW1, neb1, neW2, neb2,
      eeW1, eeb1, eeW2, eeb2,
      msgW1, msgb1, msgW2, msgb2,
      updW1, updb1, updW2, updb2,
      clsW1, clsb1, clsW2, clsb2,
      (float*)d_out, B, ngroups, nwaves);
}

// Round 6
// 61.510 us; speedup vs baseline: 4.0819x; 1.0434x over previous
//
#include <hip/hip_runtime.h>
#include <hip/hip_bf16.h>

typedef __attribute__((ext_vector_type(8))) short    s8v;  // bf16x8 MFMA operand
typedef __attribute__((ext_vector_type(4))) float    f4v;  // fp32x4 MFMA C/D
typedef __attribute__((ext_vector_type(4))) unsigned u4v;

__device__ __forceinline__ unsigned short bfu(float x){
  union { __hip_bfloat16 h; unsigned short u; } cv;
  cv.h = __float2bfloat16(x);
  return cv.u;
}
__device__ __forceinline__ unsigned pkbf(float lo, float hi){
  return (unsigned)bfu(lo) | ((unsigned)bfu(hi) << 16);
}
__device__ __forceinline__ s8v mkfrag(unsigned a, unsigned b, unsigned c_, unsigned d){
  u4v u = {a, b, c_, d};
  return __builtin_bit_cast(s8v, u);
}
__device__ __forceinline__ f4v MM(s8v a, s8v b, f4v acc){
  return __builtin_amdgcn_mfma_f32_16x16x32_bf16(a, b, acc, 0, 0, 0);
}

// Packed D-quad: p0 = (row 4g, 4g+1), p1 = (row 4g+2, 4g+3) at col c.
struct Pk { unsigned p0, p1; };
template<bool RELU>
__device__ __forceinline__ Pk mkpk(f4v d){
  float a = d[0], b = d[1], c_ = d[2], e = d[3];
  if (RELU){ a = fmaxf(a,0.f); b = fmaxf(b,0.f); c_ = fmaxf(c_,0.f); e = fmaxf(e,0.f); }
  Pk r; r.p0 = pkbf(a, b); r.p1 = pkbf(c_, e); return r;
}

// ZERO-SHUFFLE CHAINING (verified R5): D-quad fed straight into B-frag regs
// (0,1) puts feature f=4g+r at k=8g+r; A is loaded with the same row
// permutation, so no cross-lane movement between MLP stages.
__device__ __forceinline__ s8v bfragK16(Pk x){ return mkfrag(x.p0, x.p1, 0u, 0u); }
__device__ __forceinline__ s8v bfragCat(Pk x, Pk y){ return mkfrag(x.p0, x.p1, y.p0, y.p1); }

__device__ __forceinline__ s8v loadA16(const float* __restrict__ W, int K, int c, int g,
                                       float scale = 1.0f){
  int r0 = 4*g;
  unsigned u0 = pkbf(r0+0<K ? W[(r0+0)*16+c]*scale : 0.f, r0+1<K ? W[(r0+1)*16+c]*scale : 0.f);
  unsigned u1 = pkbf(r0+2<K ? W[(r0+2)*16+c]*scale : 0.f, r0+3<K ? W[(r0+3)*16+c]*scale : 0.f);
  return mkfrag(u0, u1, 0u, 0u);
}
__device__ __forceinline__ s8v loadA32(const float* __restrict__ W, int c, int g){
  int r0 = 4*g;
  unsigned u0 = pkbf(W[(r0+0)*16+c],      W[(r0+1)*16+c]);
  unsigned u1 = pkbf(W[(r0+2)*16+c],      W[(r0+3)*16+c]);
  unsigned u2 = pkbf(W[(16+r0+0)*16+c],   W[(16+r0+1)*16+c]);
  unsigned u3 = pkbf(W[(16+r0+2)*16+c],   W[(16+r0+3)*16+c]);
  return mkfrag(u0, u1, u2, u3);
}
__device__ __forceinline__ f4v ldb(const float* __restrict__ b, int g){
  f4v v; v[0] = b[4*g+0]; v[1] = b[4*g+1]; v[2] = b[4*g+2]; v[3] = b[4*g+3];
  return v;
}

// permlane swaps for the final 4-quarter reduction only (VALU, no LDS).
__device__ __forceinline__ void pl32(unsigned &a, unsigned &b){
  asm("v_permlane32_swap_b32 %0, %1" : "+v"(a), "+v"(b));
}
__device__ __forceinline__ void pl16(unsigned &a, unsigned &b){
  asm("v_permlane16_swap_b32 %0, %1" : "+v"(a), "+v"(b));
}
__device__ __forceinline__ float qsum(float part){
  unsigned pu = __builtin_bit_cast(unsigned, part), pv = pu;
  pl16(pu, pv);
  part = __builtin_bit_cast(float, pu) + __builtin_bit_cast(float, pv);
  pu = __builtin_bit_cast(unsigned, part); pv = pu;
  pl32(pu, pv);
  return __builtin_bit_cast(float, pu) + __builtin_bit_cast(float, pv);
}

// launch_bounds(256, 2): allow up to 256 VGPR so ALL weight fragments +
// biases stay register-resident across the group loop (R5's 84-VGPR alloc
// rematerialized them every iteration).
__global__ void __launch_bounds__(256, 2) egnn_ilp2(
    const float* __restrict__ nf,   const float* __restrict__ dist,
    const float* __restrict__ dz,   const float* __restrict__ s2p,
    const float* __restrict__ neW1, const float* __restrict__ neb1,
    const float* __restrict__ neW2, const float* __restrict__ neb2,
    const float* __restrict__ eeW1, const float* __restrict__ eeb1,
    const float* __restrict__ eeW2, const float* __restrict__ eeb2,
    const float* __restrict__ msgW1, const float* __restrict__ msgb1,
    const float* __restrict__ msgW2, const float* __restrict__ msgb2,
    const float* __restrict__ updW1, const float* __restrict__ updb1,
    const float* __restrict__ updW2, const float* __restrict__ updb2,
    const float* __restrict__ clsW1, const float* __restrict__ clsb1,
    const float* __restrict__ clsW2, const float* __restrict__ clsb2,
    float* __restrict__ out, int B, int npairs, int nwaves)
{
  const int lane = threadIdx.x & 63;
  const int c = lane & 15;
  const int g = lane >> 4;
  const int gwave = blockIdx.x * (blockDim.x >> 6) + (threadIdx.x >> 6);

  // ---- per-wave weight fragments (permuted rows) & bias C-inits ----
  s8v aNe1 = loadA16(neW1, 2, c, g);
  s8v aNe2 = loadA16(neW2, 16, c, g);
  s8v aEe1 = loadA16(eeW1, 3, c, g);
  s8v aEe2 = loadA16(eeW2, 16, c, g);
  s8v aCl  = loadA16(clsW1, 16, c, g, 0.5f);   // fold the node-mean 0.5
  s8v aM0[2], aM1[2], aM2[2], aU1[2], aU2[2];
  f4v bM1[2], bM2[2], bU1[2], bU2[2];
  #pragma unroll
  for (int l = 0; l < 2; ++l){
    aM0[l] = loadA32(msgW1 + l*768, c, g);            // concat rows 0..31
    aM1[l] = loadA16(msgW1 + l*768 + 512, 16, c, g);  // rows 32..47 (ee)
    aM2[l] = loadA16(msgW2 + l*256, 16, c, g);
    aU1[l] = loadA32(updW1 + l*512, c, g);            // rows 0..15 h, 16..31 msg
    aU2[l] = loadA16(updW2 + l*256, 16, c, g);
    bM1[l] = ldb(msgb1 + l*16, g);
    bM2[l] = ldb(msgb2 + l*16, g);
    bU1[l] = ldb(updb1 + l*16, g);
    bU2[l] = ldb(updb2 + l*16, g);
  }
  f4v bNe1 = ldb(neb1,g), bNe2 = ldb(neb2,g), bEe1 = ldb(eeb1,g), bEe2 = ldb(eeb2,g), bCl1 = ldb(clsb1,g);
  const float w2a = clsW2[4*g+0], w2b = clsW2[4*g+1], w2c = clsW2[4*g+2], w2d = clsW2[4*g+3];
  const float cb2 = clsb2[0];

  // ---- 2-group-ILP loop: two independent pipelines share weight regs ----
  #pragma unroll 1
  for (int p = gwave; p < npairs; p += nwaves){
    const int e0A = (2*p)     * 16;
    const int e0B = (2*p + 1) * 16;
    const int eA = min(e0A + c, B-1);
    const int eB = min(e0B + c, B-1);
    const float4 nfA = *reinterpret_cast<const float4*>(nf + (size_t)eA * 4);
    const float4 nfB = *reinterpret_cast<const float4*>(nf + (size_t)eB * 4);
    const float diA = dist[eA], zzA = dz[eA], spA = s2p[eA];
    const float diB = dist[eB], zzB = dz[eB], spB = s2p[eB];

    // ---- embeddings (interleaved A/B) ----
    s8v bA0 = mkfrag(g==0 ? pkbf(nfA.x, nfA.y) : 0u, 0u, 0u, 0u);
    s8v bB0 = mkfrag(g==0 ? pkbf(nfB.x, nfB.y) : 0u, 0u, 0u, 0u);
    s8v bA1 = mkfrag(g==0 ? pkbf(nfA.z, nfA.w) : 0u, 0u, 0u, 0u);
    s8v bB1 = mkfrag(g==0 ? pkbf(nfB.z, nfB.w) : 0u, 0u, 0u, 0u);
    s8v beA = mkfrag(g==0 ? pkbf(diA, zzA) : 0u, g==0 ? pkbf(spA, 0.f) : 0u, 0u, 0u);
    s8v beB = mkfrag(g==0 ? pkbf(diB, zzB) : 0u, g==0 ? pkbf(spB, 0.f) : 0u, 0u, 0u);
    f4v tA0 = MM(aNe1, bA0, bNe1);   f4v tB0 = MM(aNe1, bB0, bNe1);
    f4v tA1 = MM(aNe1, bA1, bNe1);   f4v tB1 = MM(aNe1, bB1, bNe1);
    f4v teA = MM(aEe1, beA, bEe1);   f4v teB = MM(aEe1, beB, bEe1);
    f4v hA0 = MM(aNe2, bfragK16(mkpk<true>(tA0)), bNe2);
    f4v hB0 = MM(aNe2, bfragK16(mkpk<true>(tB0)), bNe2);
    f4v hA1 = MM(aNe2, bfragK16(mkpk<true>(tA1)), bNe2);
    f4v hB1 = MM(aNe2, bfragK16(mkpk<true>(tB1)), bNe2);
    f4v eeA = MM(aEe2, bfragK16(mkpk<true>(teA)), bEe2);
    f4v eeB = MM(aEe2, bfragK16(mkpk<true>(teB)), bEe2);
    const s8v efA = bfragK16(mkpk<false>(eeA));
    const s8v efB = bfragK16(mkpk<false>(eeB));

    // ---- message-passing layers ----
    #pragma unroll
    for (int l = 0; l < 2; ++l){
      Pk pA0 = mkpk<false>(hA0), pA1 = mkpk<false>(hA1);
      Pk pB0 = mkpk<false>(hB0), pB1 = mkpk<false>(hB1);
      f4v eCA = MM(aM1[l], efA, bM1[l]);
      f4v eCB = MM(aM1[l], efB, bM1[l]);
      f4v mA0 = MM(aM0[l], bfragCat(pA0, pA1), eCA);
      f4v mB0 = MM(aM0[l], bfragCat(pB0, pB1), eCB);
      f4v mA1 = MM(aM0[l], bfragCat(pA1, pA0), eCA);
      f4v mB1 = MM(aM0[l], bfragCat(pB1, pB0), eCB);
      f4v gA0 = MM(aM2[l], bfragK16(mkpk<true>(mA0)), bM2[l]);
      f4v gB0 = MM(aM2[l], bfragK16(mkpk<true>(mB0)), bM2[l]);
      f4v gA1 = MM(aM2[l], bfragK16(mkpk<true>(mA1)), bM2[l]);
      f4v gB1 = MM(aM2[l], bfragK16(mkpk<true>(mB1)), bM2[l]);
      f4v uA0 = MM(aU1[l], bfragCat(pA0, mkpk<false>(gA0)), bU1[l]);
      f4v uB0 = MM(aU1[l], bfragCat(pB0, mkpk<false>(gB0)), bU1[l]);
      f4v uA1 = MM(aU1[l], bfragCat(pA1, mkpk<false>(gA1)), bU1[l]);
      f4v uB1 = MM(aU1[l], bfragCat(pB1, mkpk<false>(gB1)), bU1[l]);
      hA0 = hA0 + MM(aU2[l], bfragK16(mkpk<true>(uA0)), bU2[l]);
      hB0 = hB0 + MM(aU2[l], bfragK16(mkpk<true>(uB0)), bU2[l]);
      hA1 = hA1 + MM(aU2[l], bfragK16(mkpk<true>(uA1)), bU2[l]);
      hB1 = hB1 + MM(aU2[l], bfragK16(mkpk<true>(uB1)), bU2[l]);
    }

    // ---- classifier (0.5 pre-folded into aCl) ----
    f4v tcA = MM(aCl, bfragK16(mkpk<false>(hA0 + hA1)), bCl1);
    f4v tcB = MM(aCl, bfragK16(mkpk<false>(hB0 + hB1)), bCl1);
    float prA = fmaxf(tcA[0],0.f)*w2a + fmaxf(tcA[1],0.f)*w2b
              + fmaxf(tcA[2],0.f)*w2c + fmaxf(tcA[3],0.f)*w2d;
    float prB = fmaxf(tcB[0],0.f)*w2a + fmaxf(tcB[1],0.f)*w2b
              + fmaxf(tcB[2],0.f)*w2c + fmaxf(tcB[3],0.f)*w2d;
    prA = qsum(prA);
    prB = qsum(prB);
    if (lane < 16){
      if (e0A + c < B) out[e0A + c] = prA + cb2;
      if (e0B + c < B) out[e0B + c] = prB + cb2;
    }
  }
}

extern "C" void kernel_launch(void* const* d_in, const int* in_sizes, int n_in,
                              void* d_out, int out_size, void* d_ws, size_t ws_size,
                              hipStream_t stream) {
  const float* nf    = (const float*)d_in[0];
  const float* dist  = (const float*)d_in[1];
  const float* dz    = (const float*)d_in[2];
  const float* s2p   = (const float*)d_in[3];
  const float* neW1  = (const float*)d_in[4];
  const float* neb1  = (const float*)d_in[5];
  const float* neW2  = (const float*)d_in[6];
  const float* neb2  = (const float*)d_in[7];
  const float* eeW1  = (const float*)d_in[8];
  const float* eeb1  = (const float*)d_in[9];
  const float* eeW2  = (const float*)d_in[10];
  const float* eeb2  = (const float*)d_in[11];
  const float* msgW1 = (const float*)d_in[12];
  const float* msgb1 = (const float*)d_in[13];
  const float* msgW2 = (const float*)d_in[14];
  const float* msgb2 = (const float*)d_in[15];
  const float* updW1 = (const float*)d_in[16];
  const float* updb1 = (const float*)d_in[17];
  const float* updW2 = (const float*)d_in[18];
  const float* updb2 = (const float*)d_in[19];
  const float* clsW1 = (const float*)d_in[20];
  const float* clsb1 = (const float*)d_in[21];
  const float* clsW2 = (const float*)d_in[22];
  const float* clsb2 = (const float*)d_in[23];

  const int B = in_sizes[1];
  const int ngroups = (B + 15) / 16;
  const int npairs  = (ngroups + 1) / 2;
  int blocks = 2048;
  const int wpb = 256 / 64;
  if (blocks * wpb > npairs) blocks = (npairs + wpb - 1) / wpb;
  const int nwaves = blocks * wpb;

  egnn_ilp2<<<blocks, 256, 0, stream>>>(
      nf, dist, dz, s2p,
      neW1, neb1, neW2, neb2,
      eeW1, eeb1, eeW2, eeb2,
      msgW1, msgb1, msgW2, msgb2,
      updW1, updb1, updW2, updb2,
      clsW1, clsb1, clsW2, clsb2,
      (float*)d_out, B, npairs, nwaves);
}